// Round 6
// baseline (2310.410 us; speedup 1.0000x reference)
//
#include <hip/hip_runtime.h>
#include <hip/hip_bf16.h>

// Transformer-XL forward, MI355X gfx950.
// Round 6: GEMM occupancy + latency fix. 64x64 tiles (4x more blocks),
// double-buffered LDS with ONE barrier per K-step and register prefetch,
// padded LDS rows (72 elems) for conflict-free b128 access. Rest unchanged
// from round 5 (MFMA scores w/ rank-1 split, bf16 probs, MFMA attn_v).

#define BQ 2
#define QL 512
#define ML 512
#define CL 1024    // QLEN + MLEN
#define RL 1536    // CLEN + QLEN
#define HD 1024
#define NH 16
#define DH 64
#define FF 4096
#define NLAYER 4

typedef const float* FP;
typedef const __hip_bfloat16* BP;
typedef unsigned short u16;
typedef __attribute__((ext_vector_type(8))) __bf16 bf16x8;
typedef __attribute__((ext_vector_type(4))) float f32x4;

static __device__ __forceinline__ float b2f(__hip_bfloat16 x) { return __bfloat162float(x); }
static __device__ __forceinline__ u16 f2u(float f) {
    union { __hip_bfloat16 h; u16 u; } c; c.h = __float2bfloat16(f); return c.u;
}
static __device__ __forceinline__ float u2f(u16 u) {
    union { float f; unsigned int i; } c; c.i = ((unsigned int)u) << 16; return c.f;
}

// flags[0] = 1 if float inputs are fp32, 0 if bf16
// flags[1] = 1 if segment_matrix is int32, 0 if int8
__global__ void sniff_kernel(const unsigned int* __restrict__ ln1_gamma,
                             const unsigned char* __restrict__ seg,
                             int* __restrict__ flags) {
    if (threadIdx.x == 0) {
        flags[0] = (ln1_gamma[0] == 0x3F800000u) ? 1 : 0;
        int int32ok = 1;
        for (int i = 0; i < 256; ++i)
            if ((i & 3) != 0 && seg[i] != 0) { int32ok = 0; break; }
        flags[1] = int32ok;
    }
}

__global__ void canon_kernel(FP inf, BP inb, u16* __restrict__ out,
                             int n, const int* __restrict__ flags) {
    int i = blockIdx.x * 256 + threadIdx.x;
    if (i >= n) return;
    out[i] = flags[0] ? f2u(inf[i]) : ((const u16*)inb)[i];
}

__global__ void out_write_kernel(const u16* __restrict__ in, void* __restrict__ out,
                                 int n, const int* __restrict__ flags) {
    int i = blockIdx.x * 256 + threadIdx.x;
    if (i >= n) return;
    if (flags[0]) ((float*)out)[i] = u2f(in[i]);
    else          ((u16*)out)[i] = in[i];
}

// in: R x Cc (dual float), out: Cc x R bf16 (k-contiguous B^T)
__global__ __launch_bounds__(256) void transpose_kernel(
    FP inf, BP inb, u16* __restrict__ out, int R, int Cc,
    const int* __restrict__ flags) {
    __shared__ float t[32][33];
    const int tid = threadIdx.x;
    const int c0 = blockIdx.x * 32, r0 = blockIdx.y * 32;
    const int tc = tid & 31, tr = tid >> 5;
    const int f32 = flags[0];
    #pragma unroll
    for (int p = 0; p < 4; ++p) {
        int r = r0 + p * 8 + tr;
        size_t gi = (size_t)r * Cc + c0 + tc;
        t[p * 8 + tr][tc] = f32 ? inf[gi] : b2f(inb[gi]);
    }
    __syncthreads();
    #pragma unroll
    for (int p = 0; p < 4; ++p) {
        int c = c0 + p * 8 + tr;
        out[(size_t)c * R + r0 + tc] = f2u(t[tc][p * 8 + tr]);
    }
}

// context = concat(mems[l] (B,ML,H), X (B,QL,H)) -> (B,CL,H) bf16
__global__ void build_ctx_kernel(FP memf, BP memb, const u16* __restrict__ X,
                                 u16* __restrict__ CTX, const int* __restrict__ flags) {
    int i = blockIdx.x * 256 + threadIdx.x;
    int h = i % HD;
    int r = (i / HD) % CL;
    int b = i / (HD * CL);
    if (r < ML) {
        size_t mi = ((size_t)(b * ML + r)) * HD + h;
        CTX[i] = flags[0] ? f2u(memf[mi]) : ((const u16*)memb)[mi];
    } else {
        CTX[i] = X[((size_t)(b * QL + (r - ML))) * HD + h];
    }
}

// ---------------- MFMA bf16 GEMM: 64x64 tile, BK=64, double-buffered ----------------
// C(MxN bf16) = A(MxK bf16 row-major) * Bt^T (Bt: N x K, k contiguous)
// [+bias dual] [relu]. M%64==0, N%64==0, K%64==0.
// One __syncthreads per K-step; next tile's global loads issued before the
// barrier so they overlap the MFMA section. 72-elem LDS row stride: b128
// reads/writes hit all 32 banks uniformly (8 words/bank = wide-op minimum).
#define GPAD 72
template <bool RELU, bool HASBIAS>
__global__ __launch_bounds__(256) void mfma_gemm(
    const u16* __restrict__ A, const u16* __restrict__ Bt,
    FP biasf, BP biasb, u16* __restrict__ C,
    int M, int N, int K, const int* __restrict__ flags)
{
    __shared__ __align__(16) u16 sA[2][64 * GPAD];
    __shared__ __align__(16) u16 sB[2][64 * GPAD];
    const int tid = threadIdx.x;
    const int n0 = blockIdx.x * 64;
    const int m0 = blockIdx.y * 64;
    const int lane = tid & 63;
    const int wv = tid >> 6;
    const int wm = (wv & 1) * 32, wn = (wv >> 1) * 32;
    const int lr = lane & 15, quad = lane >> 4;
    const int srow = tid >> 2, sch = tid & 3;   // staging: 64 rows x 4 chunks of 8

    const u16* Arow = A + (size_t)(m0 + srow) * K + sch * 8;
    const u16* Brow = Bt + (size_t)(n0 + srow) * K + sch * 8;

    uint4 ra[2], rb[2];
    #pragma unroll
    for (int p = 0; p < 2; ++p) {
        ra[p] = *(const uint4*)(Arow + p * 32);
        rb[p] = *(const uint4*)(Brow + p * 32);
    }
    // prologue: stage tile 0 into buffer 0
    #pragma unroll
    for (int p = 0; p < 2; ++p) {
        *(uint4*)&sA[0][srow * GPAD + p * 32 + sch * 8] = ra[p];
        *(uint4*)&sB[0][srow * GPAD + p * 32 + sch * 8] = rb[p];
    }

    f32x4 acc[2][2];
    #pragma unroll
    for (int mt = 0; mt < 2; ++mt)
        #pragma unroll
        for (int nt = 0; nt < 2; ++nt)
            acc[mt][nt] = (f32x4){0.f, 0.f, 0.f, 0.f};

    const int nk = K >> 6;
    for (int kt = 0; kt < nk; ++kt) {
        const int cur = kt & 1;
        if (kt + 1 < nk) {                       // issue next tile's loads
            #pragma unroll
            for (int p = 0; p < 2; ++p) {
                ra[p] = *(const uint4*)(Arow + (kt + 1) * 64 + p * 32);
                rb[p] = *(const uint4*)(Brow + (kt + 1) * 64 + p * 32);
            }
        }
        __syncthreads();                          // buf[cur] stores visible
        bf16x8 af[2][2], bfm[2][2];
        #pragma unroll
        for (int mt = 0; mt < 2; ++mt)
            #pragma unroll
            for (int ks = 0; ks < 2; ++ks)
                af[mt][ks] = *(const bf16x8*)
                    &sA[cur][(wm + mt * 16 + lr) * GPAD + ks * 32 + quad * 8];
        #pragma unroll
        for (int nt = 0; nt < 2; ++nt)
            #pragma unroll
            for (int ks = 0; ks < 2; ++ks)
                bfm[nt][ks] = *(const bf16x8*)
                    &sB[cur][(wn + nt * 16 + lr) * GPAD + ks * 32 + quad * 8];
        #pragma unroll
        for (int mt = 0; mt < 2; ++mt)
            #pragma unroll
            for (int nt = 0; nt < 2; ++nt)
                #pragma unroll
                for (int ks = 0; ks < 2; ++ks)
                    acc[mt][nt] = __builtin_amdgcn_mfma_f32_16x16x32_bf16(
                        af[mt][ks], bfm[nt][ks], acc[mt][nt], 0, 0, 0);
        if (kt + 1 < nk) {                        // stage into the other buffer
            const int nxt = cur ^ 1;
            #pragma unroll
            for (int p = 0; p < 2; ++p) {
                *(uint4*)&sA[nxt][srow * GPAD + p * 32 + sch * 8] = ra[p];
                *(uint4*)&sB[nxt][srow * GPAD + p * 32 + sch * 8] = rb[p];
            }
        }
    }

    const int f32 = flags[0];
    #pragma unroll
    for (int nt = 0; nt < 2; ++nt) {
        int col = n0 + wn + nt * 16 + lr;
        float bv = 0.f;
        if (HASBIAS) bv = f32 ? biasf[col] : b2f(biasb[col]);
        #pragma unroll
        for (int mt = 0; mt < 2; ++mt) {
            int row = m0 + wm + mt * 16 + quad * 4;
            #pragma unroll
            for (int r = 0; r < 4; ++r) {
                float v = acc[mt][nt][r];
                if (HASBIAS) v += bv;
                if (RELU) v = fmaxf(v, 0.0f);
                C[(size_t)(row + r) * N + col] = f2u(v);
            }
        }
    }
}

// ---------------- ef2: (q + segment_bias) . segment_encoding[l] ----------------
__global__ void ef2_kernel(const u16* __restrict__ Qb, FP sbf, BP sbb,
                           FP sef, BP seb, float* __restrict__ EF,
                           const int* __restrict__ flags) {
    int t = blockIdx.x * 256 + threadIdx.x;
    if (t >= BQ * NH * QL) return;
    int i = t % QL;
    int n = (t / QL) % NH;
    int b = t / (QL * NH);
    float e0 = 0.f, e1 = 0.f;
    const int f32 = flags[0];
    for (int d = 0; d < DH; ++d) {
        float sbv = f32 ? sbf[n * DH + d] : b2f(sbb[n * DH + d]);
        float s0 = f32 ? sef[(0 * NH + n) * DH + d] : b2f(seb[(0 * NH + n) * DH + d]);
        float s1 = f32 ? sef[(1 * NH + n) * DH + d] : b2f(seb[(1 * NH + n) * DH + d]);
        float qv = u2f(Qb[((size_t)(b * QL + i) * NH + n) * DH + d]) + sbv;
        e0 += qv * s0;
        e1 += qv * s1;
    }
    EF[(size_t)t * 2 + 0] = e0;
    EF[(size_t)t * 2 + 1] = e1;
}

// ---------------- CK[bn][j] = cb_n . k_j ; PR[bn][rr] = pb_n . r_rr ----------------
__global__ void ckpr_kernel(const u16* __restrict__ Kb, const u16* __restrict__ Rb,
                            FP cbf, BP cbb, FP pbf, BP pbb,
                            float* __restrict__ CK, float* __restrict__ PR,
                            const int* __restrict__ flags) {
    int t = blockIdx.x * 256 + threadIdx.x;
    const int f32 = flags[0];
    if (t < 32 * CL) {
        int bn = t >> 10, j = t & (CL - 1);
        int b = bn >> 4, n = bn & 15;
        float s = 0.f;
        for (int d = 0; d < DH; ++d) {
            float c = f32 ? cbf[n * DH + d] : b2f(cbb[n * DH + d]);
            s += c * u2f(Kb[((size_t)(b * CL + j) * NH + n) * DH + d]);
        }
        CK[t] = s;
    } else {
        int t2 = t - 32 * CL;
        if (t2 >= 32 * RL) return;
        int bn = t2 / RL, rr = t2 % RL;
        int b = bn >> 4, n = bn & 15;
        float s = 0.f;
        for (int d = 0; d < DH; ++d) {
            float c = f32 ? pbf[n * DH + d] : b2f(pbb[n * DH + d]);
            s += c * u2f(Rb[((size_t)(b * RL + rr) * NH + n) * DH + d]);
        }
        PR[(size_t)bn * RL + rr] = s;
    }
}

// ---------------- MFMA scores ----------------
#define SPAD 72
__global__ __launch_bounds__(256) void scores_mfma(
    const u16* __restrict__ Qb, const u16* __restrict__ Kb,
    const u16* __restrict__ Rb, const float* __restrict__ CK,
    const float* __restrict__ PR, const float* __restrict__ EF,
    const void* __restrict__ seg, FP maskf, BP maskb,
    float* __restrict__ SC, const int* __restrict__ flags)
{
    __shared__ __align__(16) u16 sQ[64 * SPAD];
    __shared__ __align__(16) u16 sKR[192 * SPAD];
    __shared__ float sD2[4 * 16 * 132];
    const int tid = threadIdx.x;
    const int j0 = blockIdx.x * 64;
    const int i0 = blockIdx.y * 64;
    const int bn = blockIdx.z, b = bn >> 4, n = bn & 15;
    const int lane = tid & 63, w = tid >> 6;
    const int lr = lane & 15, quad = lane >> 4;
    const int baseR = 449 - i0 + j0;   // rr at p=0; in [1, 1409]

    #pragma unroll
    for (int p = 0; p < 2; ++p) {
        int c = p * 256 + tid;
        int row = c >> 3, ch = c & 7;
        *(uint4*)&sQ[row * SPAD + ch * 8] =
            *(const uint4*)&Qb[((size_t)(b * QL + i0 + row) * NH + n) * DH + ch * 8];
    }
    #pragma unroll
    for (int p = 0; p < 6; ++p) {
        int c = p * 256 + tid;
        int row = c >> 3, ch = c & 7;
        const u16* src;
        if (row < 64) {
            src = &Kb[((size_t)(b * CL + j0 + row) * NH + n) * DH + ch * 8];
        } else {
            int rr = baseR + row - 64;
            rr = rr < 0 ? 0 : (rr > RL - 1 ? RL - 1 : rr);
            src = &Rb[((size_t)(b * RL + rr) * NH + n) * DH + ch * 8];
        }
        *(uint4*)&sKR[row * SPAD + ch * 8] = *(const uint4*)src;
    }
    __syncthreads();

    f32x4 acc[12];
    #pragma unroll
    for (int i = 0; i < 12; ++i) acc[i] = (f32x4){0.f, 0.f, 0.f, 0.f};
    #pragma unroll
    for (int ks = 0; ks < 2; ++ks) {
        bf16x8 a = *(const bf16x8*)&sQ[(w * 16 + lr) * SPAD + ks * 32 + quad * 8];
        #pragma unroll
        for (int ct = 0; ct < 12; ++ct) {
            bf16x8 bfrag = *(const bf16x8*)&sKR[(ct * 16 + lr) * SPAD + ks * 32 + quad * 8];
            acc[ct] = __builtin_amdgcn_mfma_f32_16x16x32_bf16(a, bfrag, acc[ct], 0, 0, 0);
        }
    }

    float* myD = &sD2[w * 16 * 132];
    #pragma unroll
    for (int ct = 4; ct < 12; ++ct) {
        int pt = (ct - 4) * 16;
        #pragma unroll
        for (int r = 0; r < 4; ++r)
            myD[(quad * 4 + r) * 132 + pt + lr] = acc[ct][r];
    }
    __syncthreads();

    const int f32 = flags[0], s32 = flags[1];
    #pragma unroll
    for (int ct = 0; ct < 4; ++ct) {
        int jl = ct * 16 + lr, j = j0 + jl;
        float ckv = CK[(size_t)bn * CL + j];
        #pragma unroll
        for (int r = 0; r < 4; ++r) {
            int ilw = quad * 4 + r;
            int il = w * 16 + ilw;
            int i = i0 + il;
            int p = 63 - il + jl;            // in [0,126]
            float bd = myD[ilw * 132 + p];
            float pr = PR[(size_t)bn * RL + baseR + p];
            size_t mi = ((size_t)b * QL + i) * CL + j;
            int sv = s32 ? ((const int*)seg)[mi] : (int)((const signed char*)seg)[mi];
            float ef = EF[((size_t)bn * QL + i) * 2 + (sv ? 1 : 0)];
            float mk = f32 ? maskf[mi] : b2f(maskb[mi]);
            SC[((size_t)bn * QL + i) * CL + j] =
                (acc[ct][r] + bd + ckv + pr + ef) * 0.125f + mk * -1e30f;
        }
    }
}

// ---------------- softmax (CL=1024): fp32 in, bf16 probs in-place ----------------
__global__ __launch_bounds__(256) void softmax_kernel(float* __restrict__ SC) {
    const int row = blockIdx.x;
    float* p = SC + (size_t)row * CL;
    const int tid = threadIdx.x;
    const int wid = tid >> 6, lane = tid & 63;
    __shared__ float r1[4], r2[4];
    float v[4];
    #pragma unroll
    for (int c = 0; c < 4; ++c) v[c] = p[c * 256 + tid];
    float mx = fmaxf(fmaxf(v[0], v[1]), fmaxf(v[2], v[3]));
    #pragma unroll
    for (int o = 32; o > 0; o >>= 1) mx = fmaxf(mx, __shfl_xor(mx, o));
    if (lane == 0) r1[wid] = mx;
    __syncthreads();
    mx = fmaxf(fmaxf(r1[0], r1[1]), fmaxf(r1[2], r1[3]));
    float s = 0.f;
    #pragma unroll
    for (int c = 0; c < 4; ++c) { v[c] = __expf(v[c] - mx); s += v[c]; }
    #pragma unroll
    for (int o = 32; o > 0; o >>= 1) s += __shfl_xor(s, o);
    if (lane == 0) r2[wid] = s;
    __syncthreads();
    s = r2[0] + r2[1] + r2[2] + r2[3];
    float inv = 1.0f / s;
    u16* pb = (u16*)p;
    #pragma unroll
    for (int c = 0; c < 4; ++c) pb[c * 256 + tid] = f2u(v[c] * inv);
}

// ---------------- MFMA attn = probs(bf16) @ V, per (b,n) ----------------
#define VPAD 40
__global__ __launch_bounds__(256) void attn_v_mfma(
    const u16* __restrict__ PB, const u16* __restrict__ Vb, u16* __restrict__ AT)
{
    __shared__ __align__(16) u16 sP[32 * VPAD];
    __shared__ __align__(16) u16 sV[64 * VPAD];
    const int tid = threadIdx.x;
    const int i0 = blockIdx.x * 32;
    const int bn = blockIdx.y, b = bn >> 4, n = bn & 15;
    const int lane = tid & 63, w = tid >> 6;
    const int lr = lane & 15, quad = lane >> 4;
    const int rt = w >> 1;
    const int ct0 = (w & 1) * 2;
    const u16* Prow = PB + (size_t)bn * QL * 2 * CL;
    f32x4 acc[2];
    acc[0] = (f32x4){0.f, 0.f, 0.f, 0.f};
    acc[1] = (f32x4){0.f, 0.f, 0.f, 0.f};

    for (int k0 = 0; k0 < CL; k0 += 32) {
        if (tid < 128) {
            int row = tid >> 2, ch = tid & 3;
            *(uint4*)&sP[row * VPAD + ch * 8] =
                *(const uint4*)&Prow[(size_t)(i0 + row) * 2 * CL + k0 + ch * 8];
        }
        {
            int j = tid >> 3, d0 = (tid & 7) * 8;
            u16 tmp[8];
            *(uint4*)tmp = *(const uint4*)&Vb[((size_t)(b * CL + k0 + j) * NH + n) * DH + d0];
            #pragma unroll
            for (int q2 = 0; q2 < 8; ++q2) sV[(d0 + q2) * VPAD + j] = tmp[q2];
        }
        __syncthreads();
        bf16x8 a = *(const bf16x8*)&sP[(rt * 16 + lr) * VPAD + quad * 8];
        #pragma unroll
        for (int c = 0; c < 2; ++c) {
            bf16x8 bfrag = *(const bf16x8*)&sV[((ct0 + c) * 16 + lr) * VPAD + quad * 8];
            acc[c] = __builtin_amdgcn_mfma_f32_16x16x32_bf16(a, bfrag, acc[c], 0, 0, 0);
        }
        __syncthreads();
    }
    #pragma unroll
    for (int c = 0; c < 2; ++c) {
        int d = (ct0 + c) * 16 + lr;
        #pragma unroll
        for (int r = 0; r < 4; ++r) {
            int i = i0 + rt * 16 + quad * 4 + r;
            AT[((size_t)(b * QL + i) * NH + n) * DH + d] = f2u(acc[c][r]);
        }
    }
}

// ---------------- O = LayerNorm(A + B) * gamma + beta ----------------
__global__ __launch_bounds__(256) void add_ln_kernel(const u16* __restrict__ A,
                                                     const u16* __restrict__ Bv,
                                                     FP gf, BP gb, FP bef, BP beb,
                                                     u16* __restrict__ O,
                                                     const int* __restrict__ flags) {
    const int row = blockIdx.x;
    const int tid = threadIdx.x;
    const int wid = tid >> 6, lane = tid & 63;
    __shared__ float r1[4], r2[4];
    const u16* a = A + (size_t)row * HD;
    const u16* bb = Bv + (size_t)row * HD;
    float v[4];
    #pragma unroll
    for (int c = 0; c < 4; ++c) { int h = c * 256 + tid; v[c] = u2f(a[h]) + u2f(bb[h]); }
    float s = v[0] + v[1] + v[2] + v[3];
    #pragma unroll
    for (int o = 32; o > 0; o >>= 1) s += __shfl_xor(s, o);
    if (lane == 0) r1[wid] = s;
    __syncthreads();
    float mu = (r1[0] + r1[1] + r1[2] + r1[3]) * (1.0f / HD);
    float q = 0.f;
    #pragma unroll
    for (int c = 0; c < 4; ++c) { float d = v[c] - mu; q += d * d; }
    #pragma unroll
    for (int o = 32; o > 0; o >>= 1) q += __shfl_xor(q, o);
    if (lane == 0) r2[wid] = q;
    __syncthreads();
    float var = (r2[0] + r2[1] + r2[2] + r2[3]) * (1.0f / HD);
    float inv = rsqrtf(var + 1e-12f);
    const int f32 = flags[0];
    #pragma unroll
    for (int c = 0; c < 4; ++c) {
        int h = c * 256 + tid;
        float g = f32 ? gf[h] : b2f(gb[h]);
        float be = f32 ? bef[h] : b2f(beb[h]);
        O[(size_t)row * HD + h] = f2u((v[c] - mu) * inv * g + be);
    }
}

extern "C" void kernel_launch(void* const* d_in, const int* in_sizes, int n_in,
                              void* d_out, int out_size, void* d_ws, size_t ws_size,
                              hipStream_t stream) {
    (void)in_sizes; (void)n_in; (void)out_size; (void)ws_size;
    const void* content_stream = d_in[0];
    const void* content_mask   = d_in[1];
    const void* pos_enc        = d_in[2];
    const void* seg_mat        = d_in[3];
    const void* mems           = d_in[4];
    const void* w_q            = d_in[5];
    const void* w_k            = d_in[6];
    const void* w_v            = d_in[7];
    const void* w_r            = d_in[8];
    const void* w_o            = d_in[9];
    const void* ffn_w1         = d_in[10];
    const void* ffn_b1         = d_in[11];
    const void* ffn_w2         = d_in[12];
    const void* ffn_b2         = d_in[13];
    const void* ln1_g          = d_in[14];
    const void* ln1_b          = d_in[15];
    const void* ln2_g          = d_in[16];
    const void* ln2_b          = d_in[17];
    const void* cb             = d_in[18];
    const void* pb             = d_in[19];
    const void* sb             = d_in[20];
    const void* se             = d_in[21];

    float* SC    = (float*)d_ws;              // scores / bf16 probs / F1
    float* EF    = SC + 16777216;
    float* CK    = EF + 32768;
    float* PR    = CK + 32768;
    int*   flags = (int*)(PR + 49152);
    u16*   bws   = (u16*)(flags + 16);

    u16* X   = bws;               u16* Y   = X   + 1048576;
    u16* CTX = Y   + 1048576;     u16* Qb  = CTX + 2097152;
    u16* Kb  = Qb  + 1048576;     u16* Vb  = Kb  + 2097152;
    u16* Rb  = Vb  + 2097152;     u16* PE  = Rb  + 3145728;
    u16* AT  = PE  + 3145728;     u16* AO  = AT  + 1048576;
    u16* F2  = AO  + 1048576;
    u16* WQT = F2  + 1048576;     u16* WKT = WQT + 1048576;
    u16* WVT = WKT + 1048576;     u16* WRT = WVT + 1048576;
    u16* WOc = WRT + 1048576;     u16* W1T = WOc + 1048576;
    u16* W2T = W1T + 4194304;
    u16* F1  = (u16*)SC;          // alias: probs consumed before FFN1 writes

    const size_t wstride   = (size_t)HD * HD;
    const size_t memstride = (size_t)BQ * ML * HD;

    const dim3 blk(256);
    #define DUAL(base, off) ((FP)(base) + (off)), ((BP)(base) + (off))

    sniff_kernel<<<dim3(1), dim3(64), 0, stream>>>(
        (const unsigned int*)ln1_g, (const unsigned char*)seg_mat, flags);

    canon_kernel<<<dim3((BQ * QL * HD) / 256), blk, 0, stream>>>(
        DUAL(content_stream, 0), X, BQ * QL * HD, flags);
    canon_kernel<<<dim3((BQ * RL * HD) / 256), blk, 0, stream>>>(
        DUAL(pos_enc, 0), PE, BQ * RL * HD, flags);

    for (int l = 0; l < NLAYER; ++l) {
        transpose_kernel<<<dim3(32, 32), blk, 0, stream>>>(
            DUAL(w_q, (size_t)l * wstride), WQT, HD, HD, flags);
        transpose_kernel<<<dim3(32, 32), blk, 0, stream>>>(
            DUAL(w_k, (size_t)l * wstride), WKT, HD, HD, flags);
        transpose_kernel<<<dim3(32, 32), blk, 0, stream>>>(
            DUAL(w_v, (size_t)l * wstride), WVT, HD, HD, flags);
        transpose_kernel<<<dim3(32, 32), blk, 0, stream>>>(
            DUAL(w_r, (size_t)l * wstride), WRT, HD, HD, flags);
        canon_kernel<<<dim3((HD * HD) / 256), blk, 0, stream>>>(
            DUAL(w_o, (size_t)l * wstride), WOc, HD * HD, flags);
        transpose_kernel<<<dim3(FF / 32, HD / 32), blk, 0, stream>>>(
            DUAL(ffn_w1, (size_t)l * HD * FF), W1T, HD, FF, flags);
        transpose_kernel<<<dim3(HD / 32, FF / 32), blk, 0, stream>>>(
            DUAL(ffn_w2, (size_t)l * FF * HD), W2T, FF, HD, flags);

        build_ctx_kernel<<<dim3((BQ * CL * HD) / 256), blk, 0, stream>>>(
            DUAL(mems, (size_t)l * memstride), X, CTX, flags);

        mfma_gemm<false, false><<<dim3(HD / 64, (BQ * QL) / 64), blk, 0, stream>>>(
            X, WQT, (FP)nullptr, (BP)nullptr, Qb, BQ * QL, HD, HD, flags);
        mfma_gemm<false, false><<<dim3(HD / 64, (BQ * CL) / 64), blk, 0, stream>>>(
            CTX, WKT, (FP)nullptr, (BP)nullptr, Kb, BQ * CL, HD, HD, flags);
        mfma_gemm<false, false><<<dim3(HD / 64, (BQ * CL) / 64), blk, 0, stream>>>(
            CTX, WVT, (FP)nullptr, (BP)nullptr, Vb, BQ * CL, HD, HD, flags);
        mfma_gemm<false, false><<<dim3(HD / 64, (BQ * RL) / 64), blk, 0, stream>>>(
            PE, WRT, (FP)nullptr, (BP)nullptr, Rb, BQ * RL, HD, HD, flags);

        ef2_kernel<<<dim3((BQ * NH * QL) / 256), blk, 0, stream>>>(
            Qb, DUAL(sb, 0), DUAL(se, (size_t)l * 2 * NH * DH), EF, flags);
        ckpr_kernel<<<dim3((32 * CL + 32 * RL) / 256), blk, 0, stream>>>(
            Kb, Rb, DUAL(cb, 0), DUAL(pb, 0), CK, PR, flags);

        scores_mfma<<<dim3(CL / 64, QL / 64, BQ * NH), blk, 0, stream>>>(
            Qb, Kb, Rb, CK, PR, EF, seg_mat, DUAL(content_mask, 0), SC, flags);

        softmax_kernel<<<dim3(BQ * NH * QL), blk, 0, stream>>>(SC);

        attn_v_mfma<<<dim3(QL / 32, BQ * NH), blk, 0, stream>>>(
            (const u16*)SC, Vb, AT);

        mfma_gemm<false, false><<<dim3(HD / 64, (BQ * QL) / 64), blk, 0, stream>>>(
            AT, WOc, (FP)nullptr, (BP)nullptr, AO, BQ * QL, HD, HD, flags);

        add_ln_kernel<<<dim3(BQ * QL), blk, 0, stream>>>(
            AO, X, DUAL(ln1_g, (size_t)l * HD), DUAL(ln1_b, (size_t)l * HD), Y, flags);

        mfma_gemm<true, true><<<dim3(FF / 64, (BQ * QL) / 64), blk, 0, stream>>>(
            Y, W1T, DUAL(ffn_b1, (size_t)l * FF), F1, BQ * QL, FF, HD, flags);
        mfma_gemm<false, true><<<dim3(HD / 64, (BQ * QL) / 64), blk, 0, stream>>>(
            F1, W2T, DUAL(ffn_b2, (size_t)l * HD), F2, BQ * QL, HD, FF, flags);

        add_ln_kernel<<<dim3(BQ * QL), blk, 0, stream>>>(
            F2, Y, DUAL(ln2_g, (size_t)l * HD), DUAL(ln2_b, (size_t)l * HD), X, flags);
    }
    #undef DUAL

    out_write_kernel<<<dim3((BQ * QL * HD) / 256), blk, 0, stream>>>(
        X, d_out, BQ * QL * HD, flags);
}